// Round 1
// baseline (411.845 us; speedup 1.0000x reference)
//
#include <hip/hip_runtime.h>
#include <hip/hip_bf16.h>
#include <hip/hip_fp16.h>
#include <math.h>

#define N_NODES 50000
#define N_EDGES 800000
#define HC      128     // HEADS*HID
#define OUTD    64

// ---------------- CSR build ----------------

__global__ void k_deg(const int* __restrict__ dst, int* __restrict__ deg, int e_cnt) {
    int e = blockIdx.x * blockDim.x + threadIdx.x;
    if (e < e_cnt) atomicAdd(&deg[dst[e]], 1);
}

// hierarchical scan: 49 blocks of 1024 -> 1 wave -> add-down
__global__ void k_scan_up(const int* __restrict__ deg, int* __restrict__ off,
                          int* __restrict__ bsum, int n) {
    __shared__ int wsum[16];
    __shared__ int wexc[16];
    const int lane = threadIdx.x & 63;
    const int wid  = threadIdx.x >> 6;
    int i = blockIdx.x * 1024 + threadIdx.x;
    int v = (i < n) ? deg[i] : 0;
    int incl = v;
    #pragma unroll
    for (int s = 1; s < 64; s <<= 1) {
        int t = __shfl_up(incl, s, 64);
        if (lane >= s) incl += t;
    }
    if (lane == 63) wsum[wid] = incl;
    __syncthreads();
    if (wid == 0 && lane < 16) {
        int w = wsum[lane];
        int wi = w;
        #pragma unroll
        for (int s = 1; s < 16; s <<= 1) {
            int t = __shfl_up(wi, s, 64);
            if (lane >= s) wi += t;
        }
        wexc[lane] = wi - w;
    }
    __syncthreads();
    int ex = wexc[wid] + incl - v;     // exclusive within block
    if (i < n) off[i] = ex;
    if (threadIdx.x == 1023) bsum[blockIdx.x] = ex + v;   // block total
}

__global__ void k_scan_mid(const int* __restrict__ bsum, int* __restrict__ boff,
                           int nb, int* __restrict__ off, int n) {
    int lane = threadIdx.x;   // 64 threads, nb <= 64
    int v = (lane < nb) ? bsum[lane] : 0;
    int incl = v;
    #pragma unroll
    for (int s = 1; s < 64; s <<= 1) {
        int t = __shfl_up(incl, s, 64);
        if (lane >= s) incl += t;
    }
    if (lane < nb) boff[lane] = incl - v;
    if (lane == 63) off[n] = incl;     // grand total
}

__global__ void k_scan_down(int* __restrict__ off, const int* __restrict__ boff,
                            int* __restrict__ cur, int n) {
    int i = blockIdx.x * 1024 + threadIdx.x;
    if (i < n) {
        int o = off[i] + boff[blockIdx.x];
        off[i] = o;
        cur[i] = o;
    }
}

__global__ void k_fill(const int* __restrict__ src, const int* __restrict__ dst,
                       int* __restrict__ cur, int* __restrict__ esrc, int e_cnt) {
    int e = blockIdx.x * blockDim.x + threadIdx.x;
    if (e < e_cnt) {
        int p = atomicAdd(&cur[dst[e]], 1);
        esrc[p] = src[e];
    }
}

// ---------------- weight prep ----------------

__global__ void k_transpose(const float* __restrict__ W, float* __restrict__ Wt,
                            int R, int C) {
    int i = blockIdx.x * blockDim.x + threadIdx.x;
    if (i < R * C) {
        int r = i / C, c = i % C;
        Wt[c * R + r] = W[i];
    }
}

__global__ void k_combine(const float* __restrict__ pW1, const float* __restrict__ pb1,
                          const float* __restrict__ pW2, const float* __restrict__ pb2,
                          float* __restrict__ Wct, float* __restrict__ bc) {
    int i = blockIdx.x * blockDim.x + threadIdx.x;
    if (i < 128 * 64) {
        int k = i >> 6, o = i & 63;
        float s = 0.f;
        for (int m = 0; m < 64; ++m) s += pW2[o * 64 + m] * pW1[m * 128 + k];
        Wct[k * 64 + o] = s;
    }
    if (i < 64) {
        float s = pb2[i];
        for (int m = 0; m < 64; ++m) s += pW2[i * 64 + m] * pb1[m];
        bc[i] = s;
    }
}

// ---------------- linear: h[n][c] = x @ Wt + b, K=128, OC=128, OUTPUT fp16 ----------------

__global__ __launch_bounds__(256) void k_lin128(const float* __restrict__ x,
                                                const float* __restrict__ Wt,
                                                const float* __restrict__ bias,
                                                __half* __restrict__ h, int n) {
    __shared__ float xs[16][132];
    int node0 = blockIdx.x * 16;
    int t = threadIdx.x;
    for (int i = t; i < 512; i += 256) {
        int row = i >> 5, col4 = i & 31;
        int gn = node0 + row;
        float4 v = (gn < n) ? ((const float4*)x)[(size_t)gn * 32 + col4]
                            : make_float4(0.f, 0.f, 0.f, 0.f);
        ((float4*)&xs[row][0])[col4] = v;
    }
    __syncthreads();
    int c4 = t & 31;
    int ng = t >> 5;
    float4 bb = ((const float4*)bias)[c4];
    float4 a0 = bb, a1 = bb;
    int n0 = ng * 2, n1 = n0 + 1;
    for (int k = 0; k < 128; ++k) {
        float4 w = ((const float4*)&Wt[k * 128])[c4];
        float x0 = xs[n0][k], x1 = xs[n1][k];
        a0.x += w.x * x0; a0.y += w.y * x0; a0.z += w.z * x0; a0.w += w.w * x0;
        a1.x += w.x * x1; a1.y += w.y * x1; a1.z += w.z * x1; a1.w += w.w * x1;
    }
    int gn0 = node0 + n0, gn1 = node0 + n1;
    union { __half2 h2[2]; uint2 u; } p0, p1;
    p0.h2[0] = __floats2half2_rn(a0.x, a0.y); p0.h2[1] = __floats2half2_rn(a0.z, a0.w);
    p1.h2[0] = __floats2half2_rn(a1.x, a1.y); p1.h2[1] = __floats2half2_rn(a1.z, a1.w);
    if (gn0 < n) *(uint2*)&h[(size_t)gn0 * 128 + c4 * 4] = p0.u;
    if (gn1 < n) *(uint2*)&h[(size_t)gn1 * 128 + c4 * 4] = p1.u;
}

// ---------------- GAT aggregate ----------------
// One wave per dst node. Wave split into two half-waves by edge parity:
//   lane = 32*half + cq ; half in {0,1} owns edges with (idx & 1) == half,
//   cq in [0,32) owns channels [cq*4, cq*4+4).
// Log2-domain deferred-max online softmax: common path is 1 exp2 per
// channel-edge (no rescale); rescale branch taken ~once per lane (first edge).
// Half-wave partials (m,z,a) merged via shfl_xor(32) at the end.

__global__ __launch_bounds__(256) void k_gat_agg(const __half* __restrict__ h,
                                                 const int* __restrict__ off,
                                                 const int* __restrict__ esrc,
                                                 const float* __restrict__ attl,
                                                 const float* __restrict__ attr,
                                                 float* __restrict__ xout, int n,
                                                 float neg_out) {
    const float L2E = 1.4426950408889634f;
    const float THR = 11.0f;            // log2-domain defer-max threshold (exp2(11)=2048)
    int wid  = threadIdx.x >> 6;
    int lane = threadIdx.x & 63;
    int node = blockIdx.x * 4 + wid;
    if (node >= n) return;
    int half = lane >> 5;               // edge parity this half-wave owns
    int cq   = lane & 31;               // channel quad index
    uint32_t cq8 = (uint32_t)cq << 3;   // byte offset of my 4 fp16 channels in a row

    const char* hb = (const char*)h;

    // attention params for my 4 channels, pre-scaled into log2 domain
    float4 alv = ((const float4*)attl)[cq];
    float4 arv = ((const float4*)attr)[cq];
    uint2 hdr = *(const uint2*)(hb + (((uint32_t)node << 8) | cq8));
    float2 hd01 = __half22float2(((const __half2*)&hdr)[0]);
    float2 hd23 = __half22float2(((const __half2*)&hdr)[1]);
    float al0 = alv.x * L2E, al1 = alv.y * L2E;
    float al2 = alv.z * L2E, al3 = alv.w * L2E;
    float ar0 = arv.x * hd01.x * L2E, ar1 = arv.y * hd01.y * L2E;
    float ar2 = arv.z * hd23.x * L2E, ar3 = arv.w * hd23.y * L2E;

    float m0 = -INFINITY, m1 = -INFINITY, m2 = -INFINITY, m3 = -INFINITY;
    float z0 = 0.f, z1 = 0.f, z2 = 0.f, z3 = 0.f;
    float a0 = 0.f, a1 = 0.f, a2 = 0.f, a3 = 0.f;

    int beg = off[node], end = off[node + 1];

#define STEP_BODY(sAv)                                                         \
    {   uint2 hv = *(const uint2*)(hb + (((uint32_t)(sAv) << 8) | cq8));       \
        float2 f01 = __half22float2(((const __half2*)&hv)[0]);                 \
        float2 f23 = __half22float2(((const __half2*)&hv)[1]);                 \
        float t0 = fmaf(al0, f01.x, ar0); t0 = fmaxf(t0, 0.2f * t0);           \
        float t1 = fmaf(al1, f01.y, ar1); t1 = fmaxf(t1, 0.2f * t1);           \
        float t2 = fmaf(al2, f23.x, ar2); t2 = fmaxf(t2, 0.2f * t2);           \
        float t3 = fmaf(al3, f23.y, ar3); t3 = fmaxf(t3, 0.2f * t3);           \
        float d0 = t0 - m0, d1 = t1 - m1, d2 = t2 - m2, d3 = t3 - m3;          \
        if (fmaxf(fmaxf(d0, d1), fmaxf(d2, d3)) > THR) {   /* rare */          \
            float n0_ = fmaxf(m0, t0), n1_ = fmaxf(m1, t1);                    \
            float n2_ = fmaxf(m2, t2), n3_ = fmaxf(m3, t3);                    \
            float s0 = (m0 >= n0_) ? 1.f : exp2f(m0 - n0_);                    \
            float s1 = (m1 >= n1_) ? 1.f : exp2f(m1 - n1_);                    \
            float s2 = (m2 >= n2_) ? 1.f : exp2f(m2 - n2_);                    \
            float s3 = (m3 >= n3_) ? 1.f : exp2f(m3 - n3_);                    \
            z0 *= s0; z1 *= s1; z2 *= s2; z3 *= s3;                            \
            a0 *= s0; a1 *= s1; a2 *= s2; a3 *= s3;                            \
            m0 = n0_; m1 = n1_; m2 = n2_; m3 = n3_;                            \
            d0 = t0 - m0; d1 = t1 - m1; d2 = t2 - m2; d3 = t3 - m3;            \
        }                                                                      \
        float e0 = exp2f(d0), e1 = exp2f(d1);                                  \
        float e2 = exp2f(d2), e3 = exp2f(d3);                                  \
        z0 += e0; z1 += e1; z2 += e2; z3 += e3;                                \
        a0 = fmaf(e0, f01.x, a0); a1 = fmaf(e1, f01.y, a1);                    \
        a2 = fmaf(e2, f23.x, a2); a3 = fmaf(e3, f23.y, a3);                    \
    }

    for (int cbeg = beg; cbeg < end; cbeg += 64) {
        int cnt = end - cbeg; if (cnt > 64) cnt = 64;
        int myS = (cbeg + lane < end) ? esrc[cbeg + lane] : 0;
        int fullp = cnt >> 1;           // steps where both halves have an edge
        #pragma unroll 2
        for (int t = 0; t < fullp; ++t) {
            int sA = __shfl(myS, 2 * t + half, 64);   // all 64 lanes active
            STEP_BODY(sA);
        }
        if (cnt & 1) {                  // one leftover even-parity edge
            int sA = __shfl(myS, cnt - 1, 64);        // shfl with full exec
            if (half == 0) STEP_BODY(sA);
        }
    }
#undef STEP_BODY

    // merge the two parity partials (online-softmax merge), full exec for shfl
#define MERGE(mc, zc, ac)                                                      \
    {   float mo = __shfl_xor(mc, 32, 64);                                     \
        float zo = __shfl_xor(zc, 32, 64);                                     \
        float ao = __shfl_xor(ac, 32, 64);                                     \
        float M  = fmaxf(mc, mo);                                              \
        float S  = (mc >= M) ? 1.f : exp2f(mc - M);                            \
        float So = (mo >= M) ? 1.f : exp2f(mo - M);                            \
        zc = zc * S + zo * So;                                                 \
        ac = ac * S + ao * So;                                                 \
    }
    MERGE(m0, z0, a0);
    MERGE(m1, z1, a1);
    MERGE(m2, z2, a2);
    MERGE(m3, z3, a3);
#undef MERGE

    if (half == 0) {
        float o0 = (z0 > 0.f) ? a0 / z0 : 0.f;
        float o1 = (z1 > 0.f) ? a1 / z1 : 0.f;
        float o2 = (z2 > 0.f) ? a2 / z2 : 0.f;
        float o3 = (z3 > 0.f) ? a3 / z3 : 0.f;
        o0 = fmaxf(o0, neg_out * o0);
        o1 = fmaxf(o1, neg_out * o1);
        o2 = fmaxf(o2, neg_out * o2);
        o3 = fmaxf(o3, neg_out * o3);
        *(float4*)&xout[(size_t)node * 128 + cq * 4] = make_float4(o0, o1, o2, o3);
    }
}

// ---------------- final linear K=128 -> 64: fp32 out + fp16 copy ----------------

__global__ __launch_bounds__(256) void k_lin64(const float* __restrict__ x,
                                               const float* __restrict__ Wct,
                                               const float* __restrict__ bc,
                                               float* __restrict__ y,
                                               __half* __restrict__ yh, int n) {
    __shared__ float xs[16][132];
    int node0 = blockIdx.x * 16;
    int t = threadIdx.x;
    for (int i = t; i < 512; i += 256) {
        int row = i >> 5, col4 = i & 31;
        int gn = node0 + row;
        float4 v = (gn < n) ? ((const float4*)x)[(size_t)gn * 32 + col4]
                            : make_float4(0.f, 0.f, 0.f, 0.f);
        ((float4*)&xs[row][0])[col4] = v;
    }
    __syncthreads();
    int l = t & 15;
    int g = t >> 4;
    float4 acc = ((const float4*)bc)[l];
    for (int k = 0; k < 128; ++k) {
        float4 w = ((const float4*)&Wct[k * 64])[l];
        float xv = xs[g][k];
        acc.x += w.x * xv; acc.y += w.y * xv; acc.z += w.z * xv; acc.w += w.w * xv;
    }
    int gn = node0 + g;
    if (gn < n) {
        ((float4*)&y[(size_t)gn * 64])[l] = acc;
        union { __half2 h2[2]; uint2 u; } p;
        p.h2[0] = __floats2half2_rn(acc.x, acc.y);
        p.h2[1] = __floats2half2_rn(acc.z, acc.w);
        *(uint2*)&yh[(size_t)gn * 64 + l * 4] = p.u;
    }
}

// ---------------- edge scores: sigmoid(dot(x[src], x[dst])), fp16 gather, 8 lanes/edge ----------------

__global__ __launch_bounds__(256) void k_edge_score(const __half* __restrict__ xh,
                                                    const int* __restrict__ src,
                                                    const int* __restrict__ dst,
                                                    float* __restrict__ out, int e_cnt) {
    int t = blockIdx.x * 256 + threadIdx.x;
    int e = t >> 3;
    int l = t & 7;
    if (e >= e_cnt) return;
    int u = src[e], v = dst[e];
    uint4 ua = ((const uint4*)&xh[(size_t)u * 64])[l];
    uint4 vb = ((const uint4*)&xh[(size_t)v * 64])[l];
    const __half2* pa = (const __half2*)&ua;
    const __half2* pb = (const __half2*)&vb;
    float d = 0.f;
    #pragma unroll
    for (int j = 0; j < 4; ++j) {
        float2 fa = __half22float2(pa[j]);
        float2 fb = __half22float2(pb[j]);
        d = fmaf(fa.x, fb.x, d);
        d = fmaf(fa.y, fb.y, d);
    }
    d += __shfl_xor(d, 1);
    d += __shfl_xor(d, 2);
    d += __shfl_xor(d, 4);
    if (l == 0) out[e] = 1.f / (1.f + __expf(-d));
}

// ---------------- launch ----------------

extern "C" void kernel_launch(void* const* d_in, const int* in_sizes, int n_in,
                              void* d_out, int out_size, void* d_ws, size_t ws_size,
                              hipStream_t stream) {
    const float* emb   = (const float*)d_in[0];
    const int*   ei    = (const int*)d_in[1];
    const float* W0    = (const float*)d_in[2];
    const float* b0    = (const float*)d_in[3];
    const float* attl0 = (const float*)d_in[4];
    const float* attr0 = (const float*)d_in[5];
    const float* W1    = (const float*)d_in[6];
    const float* b1    = (const float*)d_in[7];
    const float* attl1 = (const float*)d_in[8];
    const float* attr1 = (const float*)d_in[9];
    const float* pW1   = (const float*)d_in[10];
    const float* pb1   = (const float*)d_in[11];
    const float* pW2   = (const float*)d_in[12];
    const float* pb2   = (const float*)d_in[13];

    const int* src = ei;
    const int* dst = ei + N_EDGES;

    float* out = (float*)d_out;          // [E]
    float* xo  = out + N_EDGES;          // [N,64] fp32 node output

    char* ws = (char*)d_ws;
    size_t o = 0;
    auto alloc = [&](size_t bytes) {
        char* p = ws + o;
        o = (o + bytes + 255) & ~(size_t)255;
        return p;
    };
    int*    deg  = (int*)alloc((size_t)N_NODES * 4);
    int*    off  = (int*)alloc((size_t)(N_NODES + 1) * 4);
    int*    cur  = (int*)alloc((size_t)N_NODES * 4);
    int*    esrc = (int*)alloc((size_t)N_EDGES * 4);
    int*    bsum = (int*)alloc(64 * 4);
    int*    boff = (int*)alloc(64 * 4);
    __half* hbuf = (__half*)alloc((size_t)N_NODES * HC * 2);
    float*  xbuf = (float*)alloc((size_t)N_NODES * HC * 4);
    __half* yh   = (__half*)alloc((size_t)N_NODES * OUTD * 2);
    float*  Wt   = (float*)alloc((size_t)HC * HC * 4);
    float*  Wct  = (float*)alloc((size_t)HC * OUTD * 4);
    float*  bc   = (float*)alloc((size_t)OUTD * 4);
    (void)ws_size; (void)in_sizes; (void)n_in; (void)out_size;

    const int SCAN_NB = (N_NODES + 1023) / 1024;   // 49

    // CSR by dst
    hipMemsetAsync(deg, 0, (size_t)N_NODES * 4, stream);
    k_deg <<<(N_EDGES + 255) / 256, 256, 0, stream>>>(dst, deg, N_EDGES);
    k_scan_up  <<<SCAN_NB, 1024, 0, stream>>>(deg, off, bsum, N_NODES);
    k_scan_mid <<<1, 64, 0, stream>>>(bsum, boff, SCAN_NB, off, N_NODES);
    k_scan_down<<<SCAN_NB, 1024, 0, stream>>>(off, boff, cur, N_NODES);
    k_fill<<<(N_EDGES + 255) / 256, 256, 0, stream>>>(src, dst, cur, esrc, N_EDGES);

    // GAT layer 0
    k_transpose<<<(HC * HC + 255) / 256, 256, 0, stream>>>(W0, Wt, HC, HC);
    k_lin128<<<N_NODES / 16, 256, 0, stream>>>(emb, Wt, b0, hbuf, N_NODES);
    k_gat_agg<<<(N_NODES + 3) / 4, 256, 0, stream>>>(hbuf, off, esrc, attl0, attr0,
                                                     xbuf, N_NODES, 0.01f);
    // GAT layer 1
    k_transpose<<<(HC * HC + 255) / 256, 256, 0, stream>>>(W1, Wt, HC, HC);
    k_lin128<<<N_NODES / 16, 256, 0, stream>>>(xbuf, Wt, b1, hbuf, N_NODES);
    k_gat_agg<<<(N_NODES + 3) / 4, 256, 0, stream>>>(hbuf, off, esrc, attl1, attr1,
                                                     xbuf, N_NODES, 0.01f);

    // post_mp (combined) + node output (fp32 + fp16 copy)
    k_combine<<<(HC * OUTD + 255) / 256, 256, 0, stream>>>(pW1, pb1, pW2, pb2, Wct, bc);
    k_lin64<<<N_NODES / 16, 256, 0, stream>>>(xbuf, Wct, bc, xo, yh, N_NODES);

    // edge scores
    k_edge_score<<<(N_EDGES * 8 + 255) / 256, 256, 0, stream>>>(yh, src, dst, out, N_EDGES);
}

// Round 2
// 385.728 us; speedup vs baseline: 1.0677x; 1.0677x over previous
//
#include <hip/hip_runtime.h>
#include <hip/hip_bf16.h>
#include <hip/hip_fp16.h>
#include <math.h>

#define N_NODES 50000
#define N_EDGES 800000
#define HC      128     // HEADS*HID
#define OUTD    64

// fast exp2: single v_exp_f32 (the precise libm exp2f is a ~10-instr branchy
// sequence without fast-math -- that was round 1's regression)
#if defined(__has_builtin)
#if __has_builtin(__builtin_amdgcn_exp2f)
#define EXP2(x) __builtin_amdgcn_exp2f(x)
#endif
#endif
#ifndef EXP2
#define EXP2(x) __expf((x) * 0.69314718055994531f)
#endif

// ---------------- CSR build ----------------

__global__ void k_deg(const int* __restrict__ dst, int* __restrict__ deg, int e_cnt) {
    int e = blockIdx.x * blockDim.x + threadIdx.x;
    if (e < e_cnt) atomicAdd(&deg[dst[e]], 1);
}

// hierarchical scan: 49 blocks of 1024 -> 1 wave -> add-down
__global__ void k_scan_up(const int* __restrict__ deg, int* __restrict__ off,
                          int* __restrict__ bsum, int n) {
    __shared__ int wsum[16];
    __shared__ int wexc[16];
    const int lane = threadIdx.x & 63;
    const int wid  = threadIdx.x >> 6;
    int i = blockIdx.x * 1024 + threadIdx.x;
    int v = (i < n) ? deg[i] : 0;
    int incl = v;
    #pragma unroll
    for (int s = 1; s < 64; s <<= 1) {
        int t = __shfl_up(incl, s, 64);
        if (lane >= s) incl += t;
    }
    if (lane == 63) wsum[wid] = incl;
    __syncthreads();
    if (wid == 0 && lane < 16) {
        int w = wsum[lane];
        int wi = w;
        #pragma unroll
        for (int s = 1; s < 16; s <<= 1) {
            int t = __shfl_up(wi, s, 64);
            if (lane >= s) wi += t;
        }
        wexc[lane] = wi - w;
    }
    __syncthreads();
    int ex = wexc[wid] + incl - v;     // exclusive within block
    if (i < n) off[i] = ex;
    if (threadIdx.x == 1023) bsum[blockIdx.x] = ex + v;   // block total
}

__global__ void k_scan_mid(const int* __restrict__ bsum, int* __restrict__ boff,
                           int nb, int* __restrict__ off, int n) {
    int lane = threadIdx.x;   // 64 threads, nb <= 64
    int v = (lane < nb) ? bsum[lane] : 0;
    int incl = v;
    #pragma unroll
    for (int s = 1; s < 64; s <<= 1) {
        int t = __shfl_up(incl, s, 64);
        if (lane >= s) incl += t;
    }
    if (lane < nb) boff[lane] = incl - v;
    if (lane == 63) off[n] = incl;     // grand total
}

__global__ void k_scan_down(int* __restrict__ off, const int* __restrict__ boff,
                            int* __restrict__ cur, int n) {
    int i = blockIdx.x * 1024 + threadIdx.x;
    if (i < n) {
        int o = off[i] + boff[blockIdx.x];
        off[i] = o;
        cur[i] = o;
    }
}

__global__ void k_fill(const int* __restrict__ src, const int* __restrict__ dst,
                       int* __restrict__ cur, int* __restrict__ esrc, int e_cnt) {
    int e = blockIdx.x * blockDim.x + threadIdx.x;
    if (e < e_cnt) {
        int p = atomicAdd(&cur[dst[e]], 1);
        esrc[p] = src[e];
    }
}

// ---------------- weight prep ----------------

__global__ void k_transpose(const float* __restrict__ W, float* __restrict__ Wt,
                            int R, int C) {
    int i = blockIdx.x * blockDim.x + threadIdx.x;
    if (i < R * C) {
        int r = i / C, c = i % C;
        Wt[c * R + r] = W[i];
    }
}

__global__ void k_combine(const float* __restrict__ pW1, const float* __restrict__ pb1,
                          const float* __restrict__ pW2, const float* __restrict__ pb2,
                          float* __restrict__ Wct, float* __restrict__ bc) {
    int i = blockIdx.x * blockDim.x + threadIdx.x;
    if (i < 128 * 64) {
        int k = i >> 6, o = i & 63;
        float s = 0.f;
        for (int m = 0; m < 64; ++m) s += pW2[o * 64 + m] * pW1[m * 128 + k];
        Wct[k * 64 + o] = s;
    }
    if (i < 64) {
        float s = pb2[i];
        for (int m = 0; m < 64; ++m) s += pW2[i * 64 + m] * pb1[m];
        bc[i] = s;
    }
}

// ---------------- linear: h[n][c] = x @ Wt + b, K=128, OC=128, OUTPUT fp16 ----------------

__global__ __launch_bounds__(256) void k_lin128(const float* __restrict__ x,
                                                const float* __restrict__ Wt,
                                                const float* __restrict__ bias,
                                                __half* __restrict__ h, int n) {
    __shared__ float xs[16][132];
    int node0 = blockIdx.x * 16;
    int t = threadIdx.x;
    for (int i = t; i < 512; i += 256) {
        int row = i >> 5, col4 = i & 31;
        int gn = node0 + row;
        float4 v = (gn < n) ? ((const float4*)x)[(size_t)gn * 32 + col4]
                            : make_float4(0.f, 0.f, 0.f, 0.f);
        ((float4*)&xs[row][0])[col4] = v;
    }
    __syncthreads();
    int c4 = t & 31;
    int ng = t >> 5;
    float4 bb = ((const float4*)bias)[c4];
    float4 a0 = bb, a1 = bb;
    int n0 = ng * 2, n1 = n0 + 1;
    for (int k = 0; k < 128; ++k) {
        float4 w = ((const float4*)&Wt[k * 128])[c4];
        float x0 = xs[n0][k], x1 = xs[n1][k];
        a0.x += w.x * x0; a0.y += w.y * x0; a0.z += w.z * x0; a0.w += w.w * x0;
        a1.x += w.x * x1; a1.y += w.y * x1; a1.z += w.z * x1; a1.w += w.w * x1;
    }
    int gn0 = node0 + n0, gn1 = node0 + n1;
    union { __half2 h2[2]; uint2 u; } p0, p1;
    p0.h2[0] = __floats2half2_rn(a0.x, a0.y); p0.h2[1] = __floats2half2_rn(a0.z, a0.w);
    p1.h2[0] = __floats2half2_rn(a1.x, a1.y); p1.h2[1] = __floats2half2_rn(a1.z, a1.w);
    if (gn0 < n) *(uint2*)&h[(size_t)gn0 * 128 + c4 * 4] = p0.u;
    if (gn1 < n) *(uint2*)&h[(size_t)gn1 * 128 + c4 * 4] = p1.u;
}

// ---------------- GAT aggregate ----------------
// One wave per dst node, split into two half-waves by edge parity:
//   lane = 32*half + cq; half owns edges with (idx&1)==half, cq owns 4 channels.
// Log2-domain deferred-max online softmax, m initialized to 0:
//   scores here are O(+-5) in log2 domain, so d = t - m stays below THR=11 and
//   the (wave-uniform, __any) rescale branch ~never executes. Common path is
//   1 v_exp_f32 per channel-edge. Deferred values bounded by 2^11 * deg -- f32 safe.
// Half-wave partials (m,z,a) merged via shfl_xor(32) at the end.

__global__ __launch_bounds__(256) void k_gat_agg(const __half* __restrict__ h,
                                                 const int* __restrict__ off,
                                                 const int* __restrict__ esrc,
                                                 const float* __restrict__ attl,
                                                 const float* __restrict__ attr,
                                                 float* __restrict__ xout, int n,
                                                 float neg_out) {
    const float L2E = 1.4426950408889634f;
    const float THR = 11.0f;            // log2-domain defer-max threshold (2^11 = 2048)
    int wid  = threadIdx.x >> 6;
    int lane = threadIdx.x & 63;
    int node = blockIdx.x * 4 + wid;
    if (node >= n) return;
    int half = lane >> 5;               // edge parity this half-wave owns
    int cq   = lane & 31;               // channel quad index
    uint32_t cq8 = (uint32_t)cq << 3;   // byte offset of my 4 fp16 channels in a row

    const char* hb = (const char*)h;

    // attention params for my 4 channels, pre-scaled into log2 domain
    float4 alv = ((const float4*)attl)[cq];
    float4 arv = ((const float4*)attr)[cq];
    uint2 hdr = *(const uint2*)(hb + (((uint32_t)node << 8) | cq8));
    float2 hd01 = __half22float2(((const __half2*)&hdr)[0]);
    float2 hd23 = __half22float2(((const __half2*)&hdr)[1]);
    float al0 = alv.x * L2E, al1 = alv.y * L2E;
    float al2 = alv.z * L2E, al3 = alv.w * L2E;
    float ar0 = arv.x * hd01.x * L2E, ar1 = arv.y * hd01.y * L2E;
    float ar2 = arv.z * hd23.x * L2E, ar3 = arv.w * hd23.y * L2E;

    float m0 = 0.f, m1 = 0.f, m2 = 0.f, m3 = 0.f;
    float z0 = 0.f, z1 = 0.f, z2 = 0.f, z3 = 0.f;
    float a0 = 0.f, a1 = 0.f, a2 = 0.f, a3 = 0.f;

    int beg = off[node], end = off[node + 1];

#define STEP_BODY(sAv)                                                         \
    {   uint32_t vo = ((uint32_t)(sAv) << 8) | cq8;                            \
        uint2 hv = *(const uint2*)(hb + vo);                                   \
        float2 f01 = __half22float2(((const __half2*)&hv)[0]);                 \
        float2 f23 = __half22float2(((const __half2*)&hv)[1]);                 \
        float t0 = fmaf(al0, f01.x, ar0); t0 = fmaxf(t0, 0.2f * t0);           \
        float t1 = fmaf(al1, f01.y, ar1); t1 = fmaxf(t1, 0.2f * t1);           \
        float t2 = fmaf(al2, f23.x, ar2); t2 = fmaxf(t2, 0.2f * t2);           \
        float t3 = fmaf(al3, f23.y, ar3); t3 = fmaxf(t3, 0.2f * t3);           \
        float d0 = t0 - m0, d1 = t1 - m1, d2 = t2 - m2, d3 = t3 - m3;          \
        float dmax = fmaxf(fmaxf(d0, d1), fmaxf(d2, d3));                      \
        if (__any(dmax > THR)) {        /* wave-uniform, ~never taken */       \
            float n0_ = fmaxf(m0, t0), n1_ = fmaxf(m1, t1);                    \
            float n2_ = fmaxf(m2, t2), n3_ = fmaxf(m3, t3);                    \
            float s0 = EXP2(m0 - n0_), s1 = EXP2(m1 - n1_);                    \
            float s2 = EXP2(m2 - n2_), s3 = EXP2(m3 - n3_);                    \
            z0 *= s0; z1 *= s1; z2 *= s2; z3 *= s3;                            \
            a0 *= s0; a1 *= s1; a2 *= s2; a3 *= s3;                            \
            m0 = n0_; m1 = n1_; m2 = n2_; m3 = n3_;                            \
            d0 = t0 - m0; d1 = t1 - m1; d2 = t2 - m2; d3 = t3 - m3;            \
        }                                                                      \
        float e0 = EXP2(d0), e1 = EXP2(d1);                                    \
        float e2 = EXP2(d2), e3 = EXP2(d3);                                    \
        z0 += e0; z1 += e1; z2 += e2; z3 += e3;                                \
        a0 = fmaf(e0, f01.x, a0); a1 = fmaf(e1, f01.y, a1);                    \
        a2 = fmaf(e2, f23.x, a2); a3 = fmaf(e3, f23.y, a3);                    \
    }

    for (int cbeg = beg; cbeg < end; cbeg += 64) {
        int cnt = end - cbeg; if (cnt > 64) cnt = 64;
        int myS = (cbeg + lane < end) ? esrc[cbeg + lane] : 0;
        int fullp = cnt >> 1;           // steps where both halves have an edge
        #pragma unroll 2
        for (int t = 0; t < fullp; ++t) {
            int sA = __shfl(myS, 2 * t + half, 64);   // all 64 lanes active
            STEP_BODY(sA);
        }
        if (cnt & 1) {                  // one leftover even-parity edge
            int sA = __shfl(myS, cnt - 1, 64);        // shfl with full exec
            if (half == 0) STEP_BODY(sA);
        }
    }
#undef STEP_BODY

    // merge the two parity partials (online-softmax merge), full exec for shfl
#define MERGE(mc, zc, ac)                                                      \
    {   float mo = __shfl_xor(mc, 32, 64);                                     \
        float zo = __shfl_xor(zc, 32, 64);                                     \
        float ao = __shfl_xor(ac, 32, 64);                                     \
        float M  = fmaxf(mc, mo);                                              \
        float S  = (mc >= M) ? 1.f : EXP2(mc - M);                             \
        float So = (mo >= M) ? 1.f : EXP2(mo - M);                             \
        zc = zc * S + zo * So;                                                 \
        ac = ac * S + ao * So;                                                 \
    }
    MERGE(m0, z0, a0);
    MERGE(m1, z1, a1);
    MERGE(m2, z2, a2);
    MERGE(m3, z3, a3);
#undef MERGE

    if (half == 0) {
        float o0 = (z0 > 0.f) ? a0 / z0 : 0.f;
        float o1 = (z1 > 0.f) ? a1 / z1 : 0.f;
        float o2 = (z2 > 0.f) ? a2 / z2 : 0.f;
        float o3 = (z3 > 0.f) ? a3 / z3 : 0.f;
        o0 = fmaxf(o0, neg_out * o0);
        o1 = fmaxf(o1, neg_out * o1);
        o2 = fmaxf(o2, neg_out * o2);
        o3 = fmaxf(o3, neg_out * o3);
        *(float4*)&xout[(size_t)node * 128 + cq * 4] = make_float4(o0, o1, o2, o3);
    }
}

// ---------------- final linear K=128 -> 64: fp32 out + fp16 copy ----------------

__global__ __launch_bounds__(256) void k_lin64(const float* __restrict__ x,
                                               const float* __restrict__ Wct,
                                               const float* __restrict__ bc,
                                               float* __restrict__ y,
                                               __half* __restrict__ yh, int n) {
    __shared__ float xs[16][132];
    int node0 = blockIdx.x * 16;
    int t = threadIdx.x;
    for (int i = t; i < 512; i += 256) {
        int row = i >> 5, col4 = i & 31;
        int gn = node0 + row;
        float4 v = (gn < n) ? ((const float4*)x)[(size_t)gn * 32 + col4]
                            : make_float4(0.f, 0.f, 0.f, 0.f);
        ((float4*)&xs[row][0])[col4] = v;
    }
    __syncthreads();
    int l = t & 15;
    int g = t >> 4;
    float4 acc = ((const float4*)bc)[l];
    for (int k = 0; k < 128; ++k) {
        float4 w = ((const float4*)&Wct[k * 64])[l];
        float xv = xs[g][k];
        acc.x += w.x * xv; acc.y += w.y * xv; acc.z += w.z * xv; acc.w += w.w * xv;
    }
    int gn = node0 + g;
    if (gn < n) {
        ((float4*)&y[(size_t)gn * 64])[l] = acc;
        union { __half2 h2[2]; uint2 u; } p;
        p.h2[0] = __floats2half2_rn(acc.x, acc.y);
        p.h2[1] = __floats2half2_rn(acc.z, acc.w);
        *(uint2*)&yh[(size_t)gn * 64 + l * 4] = p.u;
    }
}

// ---------------- edge scores: sigmoid(dot(x[src], x[dst])), fp16 gather, 8 lanes/edge ----------------

__global__ __launch_bounds__(256) void k_edge_score(const __half* __restrict__ xh,
                                                    const int* __restrict__ src,
                                                    const int* __restrict__ dst,
                                                    float* __restrict__ out, int e_cnt) {
    int t = blockIdx.x * 256 + threadIdx.x;
    int e = t >> 3;
    int l = t & 7;
    if (e >= e_cnt) return;
    int u = src[e], v = dst[e];
    uint4 ua = ((const uint4*)&xh[(size_t)u * 64])[l];
    uint4 vb = ((const uint4*)&xh[(size_t)v * 64])[l];
    const __half2* pa = (const __half2*)&ua;
    const __half2* pb = (const __half2*)&vb;
    float d = 0.f;
    #pragma unroll
    for (int j = 0; j < 4; ++j) {
        float2 fa = __half22float2(pa[j]);
        float2 fb = __half22float2(pb[j]);
        d = fmaf(fa.x, fb.x, d);
        d = fmaf(fa.y, fb.y, d);
    }
    d += __shfl_xor(d, 1);
    d += __shfl_xor(d, 2);
    d += __shfl_xor(d, 4);
    if (l == 0) out[e] = 1.f / (1.f + __expf(-d));
}

// ---------------- launch ----------------

extern "C" void kernel_launch(void* const* d_in, const int* in_sizes, int n_in,
                              void* d_out, int out_size, void* d_ws, size_t ws_size,
                              hipStream_t stream) {
    const float* emb   = (const float*)d_in[0];
    const int*   ei    = (const int*)d_in[1];
    const float* W0    = (const float*)d_in[2];
    const float* b0    = (const float*)d_in[3];
    const float* attl0 = (const float*)d_in[4];
    const float* attr0 = (const float*)d_in[5];
    const float* W1    = (const float*)d_in[6];
    const float* b1    = (const float*)d_in[7];
    const float* attl1 = (const float*)d_in[8];
    const float* attr1 = (const float*)d_in[9];
    const float* pW1   = (const float*)d_in[10];
    const float* pb1   = (const float*)d_in[11];
    const float* pW2   = (const float*)d_in[12];
    const float* pb2   = (const float*)d_in[13];

    const int* src = ei;
    const int* dst = ei + N_EDGES;

    float* out = (float*)d_out;          // [E]
    float* xo  = out + N_EDGES;          // [N,64] fp32 node output

    char* ws = (char*)d_ws;
    size_t o = 0;
    auto alloc = [&](size_t bytes) {
        char* p = ws + o;
        o = (o + bytes + 255) & ~(size_t)255;
        return p;
    };
    int*    deg  = (int*)alloc((size_t)N_NODES * 4);
    int*    off  = (int*)alloc((size_t)(N_NODES + 1) * 4);
    int*    cur  = (int*)alloc((size_t)N_NODES * 4);
    int*    esrc = (int*)alloc((size_t)N_EDGES * 4);
    int*    bsum = (int*)alloc(64 * 4);
    int*    boff = (int*)alloc(64 * 4);
    __half* hbuf = (__half*)alloc((size_t)N_NODES * HC * 2);
    float*  xbuf = (float*)alloc((size_t)N_NODES * HC * 4);
    __half* yh   = (__half*)alloc((size_t)N_NODES * OUTD * 2);
    float*  Wt   = (float*)alloc((size_t)HC * HC * 4);
    float*  Wct  = (float*)alloc((size_t)HC * OUTD * 4);
    float*  bc   = (float*)alloc((size_t)OUTD * 4);
    (void)ws_size; (void)in_sizes; (void)n_in; (void)out_size;

    const int SCAN_NB = (N_NODES + 1023) / 1024;   // 49

    // CSR by dst
    hipMemsetAsync(deg, 0, (size_t)N_NODES * 4, stream);
    k_deg <<<(N_EDGES + 255) / 256, 256, 0, stream>>>(dst, deg, N_EDGES);
    k_scan_up  <<<SCAN_NB, 1024, 0, stream>>>(deg, off, bsum, N_NODES);
    k_scan_mid <<<1, 64, 0, stream>>>(bsum, boff, SCAN_NB, off, N_NODES);
    k_scan_down<<<SCAN_NB, 1024, 0, stream>>>(off, boff, cur, N_NODES);
    k_fill<<<(N_EDGES + 255) / 256, 256, 0, stream>>>(src, dst, cur, esrc, N_EDGES);

    // GAT layer 0
    k_transpose<<<(HC * HC + 255) / 256, 256, 0, stream>>>(W0, Wt, HC, HC);
    k_lin128<<<N_NODES / 16, 256, 0, stream>>>(emb, Wt, b0, hbuf, N_NODES);
    k_gat_agg<<<(N_NODES + 3) / 4, 256, 0, stream>>>(hbuf, off, esrc, attl0, attr0,
                                                     xbuf, N_NODES, 0.01f);
    // GAT layer 1
    k_transpose<<<(HC * HC + 255) / 256, 256, 0, stream>>>(W1, Wt, HC, HC);
    k_lin128<<<N_NODES / 16, 256, 0, stream>>>(xbuf, Wt, b1, hbuf, N_NODES);
    k_gat_agg<<<(N_NODES + 3) / 4, 256, 0, stream>>>(hbuf, off, esrc, attl1, attr1,
                                                     xbuf, N_NODES, 0.01f);

    // post_mp (combined) + node output (fp32 + fp16 copy)
    k_combine<<<(HC * OUTD + 255) / 256, 256, 0, stream>>>(pW1, pb1, pW2, pb2, Wct, bc);
    k_lin64<<<N_NODES / 16, 256, 0, stream>>>(xbuf, Wct, bc, xo, yh, N_NODES);

    // edge scores
    k_edge_score<<<(N_EDGES * 8 + 255) / 256, 256, 0, stream>>>(yh, src, dst, out, N_EDGES);
}

// Round 4
// 321.555 us; speedup vs baseline: 1.2808x; 1.1996x over previous
//
#include <hip/hip_runtime.h>
#include <hip/hip_bf16.h>
#include <hip/hip_fp16.h>
#include <math.h>

#define N_NODES 50000
#define N_EDGES 800000
#define HC      128     // HEADS*HID
#define OUTD    64

// fast exp2: single v_exp_f32
#if defined(__has_builtin)
#if __has_builtin(__builtin_amdgcn_exp2f)
#define EXP2(x) __builtin_amdgcn_exp2f(x)
#endif
#endif
#ifndef EXP2
#define EXP2(x) __expf((x) * 0.69314718055994531f)
#endif

// ---------------- CSR build ----------------

__global__ void k_deg(const int* __restrict__ dst, int* __restrict__ deg, int e_cnt) {
    int e = blockIdx.x * blockDim.x + threadIdx.x;
    if (e < e_cnt) atomicAdd(&deg[dst[e]], 1);
}

// hierarchical scan: 49 blocks of 1024 -> 1 wave -> add-down
__global__ void k_scan_up(const int* __restrict__ deg, int* __restrict__ off,
                          int* __restrict__ bsum, int n) {
    __shared__ int wsum[16];
    __shared__ int wexc[16];
    const int lane = threadIdx.x & 63;
    const int wid  = threadIdx.x >> 6;
    int i = blockIdx.x * 1024 + threadIdx.x;
    int v = (i < n) ? deg[i] : 0;
    int incl = v;
    #pragma unroll
    for (int s = 1; s < 64; s <<= 1) {
        int t = __shfl_up(incl, s, 64);
        if (lane >= s) incl += t;
    }
    if (lane == 63) wsum[wid] = incl;
    __syncthreads();
    if (wid == 0 && lane < 16) {
        int w = wsum[lane];
        int wi = w;
        #pragma unroll
        for (int s = 1; s < 16; s <<= 1) {
            int t = __shfl_up(wi, s, 64);
            if (lane >= s) wi += t;
        }
        wexc[lane] = wi - w;
    }
    __syncthreads();
    int ex = wexc[wid] + incl - v;     // exclusive within block
    if (i < n) off[i] = ex;
    if (threadIdx.x == 1023) bsum[blockIdx.x] = ex + v;   // block total
}

__global__ void k_scan_mid(const int* __restrict__ bsum, int* __restrict__ boff,
                           int nb, int* __restrict__ off, int n) {
    int lane = threadIdx.x;   // 64 threads, nb <= 64
    int v = (lane < nb) ? bsum[lane] : 0;
    int incl = v;
    #pragma unroll
    for (int s = 1; s < 64; s <<= 1) {
        int t = __shfl_up(incl, s, 64);
        if (lane >= s) incl += t;
    }
    if (lane < nb) boff[lane] = incl - v;
    if (lane == 63) off[n] = incl;     // grand total
}

__global__ void k_scan_down(int* __restrict__ off, const int* __restrict__ boff,
                            int* __restrict__ cur, int n) {
    int i = blockIdx.x * 1024 + threadIdx.x;
    if (i < n) {
        int o = off[i] + boff[blockIdx.x];
        off[i] = o;
        cur[i] = o;
    }
}

__global__ void k_fill(const int* __restrict__ src, const int* __restrict__ dst,
                       int* __restrict__ cur, int* __restrict__ esrc, int e_cnt) {
    int e = blockIdx.x * blockDim.x + threadIdx.x;
    if (e < e_cnt) {
        int p = atomicAdd(&cur[dst[e]], 1);
        esrc[p] = src[e];
    }
}

// ---------------- weight prep ----------------

__global__ void k_transpose(const float* __restrict__ W, float* __restrict__ Wt,
                            int R, int C) {
    int i = blockIdx.x * blockDim.x + threadIdx.x;
    if (i < R * C) {
        int r = i / C, c = i % C;
        Wt[c * R + r] = W[i];
    }
}

__global__ void k_combine(const float* __restrict__ pW1, const float* __restrict__ pb1,
                          const float* __restrict__ pW2, const float* __restrict__ pb2,
                          float* __restrict__ Wct, float* __restrict__ bc) {
    int i = blockIdx.x * blockDim.x + threadIdx.x;
    if (i < 128 * 64) {
        int k = i >> 6, o = i & 63;
        float s = 0.f;
        for (int m = 0; m < 64; ++m) s += pW2[o * 64 + m] * pW1[m * 128 + k];
        Wct[k * 64 + o] = s;
    }
    if (i < 64) {
        float s = pb2[i];
        for (int m = 0; m < 64; ++m) s += pW2[i * 64 + m] * pb1[m];
        bc[i] = s;
    }
}

// ---------------- linear: h = x @ Wt + b, K=128, OC=128, out fp16 ----------------
// LDS-staged weights (round 2 was L2-BW-bound: each wave re-read 64KB Wt from
// L2 => 1.6 GB/dispatch at ~75% of L2 ceiling). Now: 32 nodes/block, Wt staged
// in two 32KB K-chunks, x staged once (16KB). 48KB LDS -> 3 blocks/CU.
// Each thread: 4 nodes x 4 channels; per k-quad: 8 ds_read_b128 + 64 FMA.
// NOTE: macro params must not be named x/y/z/w (member-access tokens get
// substituted by the preprocessor -- round 3's compile failure).

#define FMA4(acc, wv, sv)                                                      \
    acc.x = fmaf(wv.x, sv, acc.x); acc.y = fmaf(wv.y, sv, acc.y);              \
    acc.z = fmaf(wv.z, sv, acc.z); acc.w = fmaf(wv.w, sv, acc.w);

__global__ __launch_bounds__(256) void k_lin128(const float* __restrict__ x,
                                                const float* __restrict__ Wt,
                                                const float* __restrict__ bias,
                                                __half* __restrict__ h, int n) {
    __shared__ float ws[64 * 128];      // 32KB: one K-chunk of Wt (rows = k)
    __shared__ float xs[32 * 128];      // 16KB: 32 node rows
    int t = threadIdx.x;
    int node0 = blockIdx.x * 32;
    // stage x once (1024 float4, 4 per thread)
    for (int i = t; i < 1024; i += 256) {
        int row = i >> 5, c = i & 31;
        int gn = node0 + row;
        ((float4*)xs)[i] = (gn < n) ? ((const float4*)x)[(size_t)gn * 32 + c]
                                    : make_float4(0.f, 0.f, 0.f, 0.f);
    }
    int c4 = t & 31;                    // output float4 index [0,32)
    int ng = (t >> 5) * 4;              // first of my 4 nodes
    float4 bb = ((const float4*)bias)[c4];
    float4 a0 = bb, a1 = bb, a2 = bb, a3 = bb;
    const float4* xr0 = (const float4*)&xs[(ng + 0) * 128];
    const float4* xr1 = (const float4*)&xs[(ng + 1) * 128];
    const float4* xr2 = (const float4*)&xs[(ng + 2) * 128];
    const float4* xr3 = (const float4*)&xs[(ng + 3) * 128];

    for (int chunk = 0; chunk < 2; ++chunk) {
        __syncthreads();                // x ready (it=0) / ws no longer read (it=1)
        const float4* wsrc = (const float4*)&Wt[chunk * 64 * 128];
        for (int i = t; i < 2048; i += 256)
            ((float4*)ws)[i] = wsrc[i];
        __syncthreads();
        int kb = chunk * 16;
        #pragma unroll 4
        for (int k4 = 0; k4 < 16; ++k4) {
            float4 xv0 = xr0[kb + k4];
            float4 xv1 = xr1[kb + k4];
            float4 xv2 = xr2[kb + k4];
            float4 xv3 = xr3[kb + k4];
            const float* wr = &ws[k4 * 512];
            float4 w0 = ((const float4*)&wr[0])[c4];
            float4 w1 = ((const float4*)&wr[128])[c4];
            float4 w2 = ((const float4*)&wr[256])[c4];
            float4 w3 = ((const float4*)&wr[384])[c4];
            FMA4(a0, w0, xv0.x); FMA4(a0, w1, xv0.y); FMA4(a0, w2, xv0.z); FMA4(a0, w3, xv0.w);
            FMA4(a1, w0, xv1.x); FMA4(a1, w1, xv1.y); FMA4(a1, w2, xv1.z); FMA4(a1, w3, xv1.w);
            FMA4(a2, w0, xv2.x); FMA4(a2, w1, xv2.y); FMA4(a2, w2, xv2.z); FMA4(a2, w3, xv2.w);
            FMA4(a3, w0, xv3.x); FMA4(a3, w1, xv3.y); FMA4(a3, w2, xv3.z); FMA4(a3, w3, xv3.w);
        }
    }

    union { __half2 h2[2]; uint2 u; } p;
    int gn = node0 + ng;
    if (gn + 0 < n) { p.h2[0] = __floats2half2_rn(a0.x, a0.y); p.h2[1] = __floats2half2_rn(a0.z, a0.w);
                      *(uint2*)&h[(size_t)(gn + 0) * 128 + c4 * 4] = p.u; }
    if (gn + 1 < n) { p.h2[0] = __floats2half2_rn(a1.x, a1.y); p.h2[1] = __floats2half2_rn(a1.z, a1.w);
                      *(uint2*)&h[(size_t)(gn + 1) * 128 + c4 * 4] = p.u; }
    if (gn + 2 < n) { p.h2[0] = __floats2half2_rn(a2.x, a2.y); p.h2[1] = __floats2half2_rn(a2.z, a2.w);
                      *(uint2*)&h[(size_t)(gn + 2) * 128 + c4 * 4] = p.u; }
    if (gn + 3 < n) { p.h2[0] = __floats2half2_rn(a3.x, a3.y); p.h2[1] = __floats2half2_rn(a3.z, a3.w);
                      *(uint2*)&h[(size_t)(gn + 3) * 128 + c4 * 4] = p.u; }
}

// ---------------- GAT aggregate (unchanged from round 2) ----------------

__global__ __launch_bounds__(256) void k_gat_agg(const __half* __restrict__ h,
                                                 const int* __restrict__ off,
                                                 const int* __restrict__ esrc,
                                                 const float* __restrict__ attl,
                                                 const float* __restrict__ attr,
                                                 float* __restrict__ xout, int n,
                                                 float neg_out) {
    const float L2E = 1.4426950408889634f;
    const float THR = 11.0f;            // log2-domain defer-max threshold (2^11 = 2048)
    int wid  = threadIdx.x >> 6;
    int lane = threadIdx.x & 63;
    int node = blockIdx.x * 4 + wid;
    if (node >= n) return;
    int half = lane >> 5;               // edge parity this half-wave owns
    int cq   = lane & 31;               // channel quad index
    uint32_t cq8 = (uint32_t)cq << 3;   // byte offset of my 4 fp16 channels in a row

    const char* hb = (const char*)h;

    float4 alv = ((const float4*)attl)[cq];
    float4 arv = ((const float4*)attr)[cq];
    uint2 hdr = *(const uint2*)(hb + (((uint32_t)node << 8) | cq8));
    float2 hd01 = __half22float2(((const __half2*)&hdr)[0]);
    float2 hd23 = __half22float2(((const __half2*)&hdr)[1]);
    float al0 = alv.x * L2E, al1 = alv.y * L2E;
    float al2 = alv.z * L2E, al3 = alv.w * L2E;
    float ar0 = arv.x * hd01.x * L2E, ar1 = arv.y * hd01.y * L2E;
    float ar2 = arv.z * hd23.x * L2E, ar3 = arv.w * hd23.y * L2E;

    float m0 = 0.f, m1 = 0.f, m2 = 0.f, m3 = 0.f;
    float z0 = 0.f, z1 = 0.f, z2 = 0.f, z3 = 0.f;
    float a0 = 0.f, a1 = 0.f, a2 = 0.f, a3 = 0.f;

    int beg = off[node], end = off[node + 1];

#define STEP_BODY(sAv)                                                         \
    {   uint32_t vo = ((uint32_t)(sAv) << 8) | cq8;                            \
        uint2 hv = *(const uint2*)(hb + vo);                                   \
        float2 f01 = __half22float2(((const __half2*)&hv)[0]);                 \
        float2 f23 = __half22float2(((const __half2*)&hv)[1]);                 \
        float t0 = fmaf(al0, f01.x, ar0); t0 = fmaxf(t0, 0.2f * t0);           \
        float t1 = fmaf(al1, f01.y, ar1); t1 = fmaxf(t1, 0.2f * t1);           \
        float t2 = fmaf(al2, f23.x, ar2); t2 = fmaxf(t2, 0.2f * t2);           \
        float t3 = fmaf(al3, f23.y, ar3); t3 = fmaxf(t3, 0.2f * t3);           \
        float d0 = t0 - m0, d1 = t1 - m1, d2 = t2 - m2, d3 = t3 - m3;          \
        float dmax = fmaxf(fmaxf(d0, d1), fmaxf(d2, d3));                      \
        if (__any(dmax > THR)) {        /* wave-uniform, ~never taken */       \
            float n0_ = fmaxf(m0, t0), n1_ = fmaxf(m1, t1);                    \
            float n2_ = fmaxf(m2, t2), n3_ = fmaxf(m3, t3);                    \
            float s0 = EXP2(m0 - n0_), s1 = EXP2(m1 - n1_);                    \
            float s2 = EXP2(m2 - n2_), s3 = EXP2(m3 - n3_);                    \
            z0 *= s0; z1 *= s1; z2 *= s2; z3 *= s3;                            \
            a0 *= s0; a1 *= s1; a2 *= s2; a3 *= s3;                            \
            m0 = n0_; m1 = n1_; m2 = n2_; m3 = n3_;                            \
            d0 = t0 - m0; d1 = t1 - m1; d2 = t2 - m2; d3 = t3 - m3;            \
        }                                                                      \
        float e0 = EXP2(d0), e1 = EXP2(d1);                                    \
        float e2 = EXP2(d2), e3 = EXP2(d3);                                    \
        z0 += e0; z1 += e1; z2 += e2; z3 += e3;                                \
        a0 = fmaf(e0, f01.x, a0); a1 = fmaf(e1, f01.y, a1);                    \
        a2 = fmaf(e2, f23.x, a2); a3 = fmaf(e3, f23.y, a3);                    \
    }

    for (int cbeg = beg; cbeg < end; cbeg += 64) {
        int cnt = end - cbeg; if (cnt > 64) cnt = 64;
        int myS = (cbeg + lane < end) ? esrc[cbeg + lane] : 0;
        int fullp = cnt >> 1;           // steps where both halves have an edge
        #pragma unroll 2
        for (int t = 0; t < fullp; ++t) {
            int sA = __shfl(myS, 2 * t + half, 64);   // all 64 lanes active
            STEP_BODY(sA);
        }
        if (cnt & 1) {                  // one leftover even-parity edge
            int sA = __shfl(myS, cnt - 1, 64);        // shfl with full exec
            if (half == 0) STEP_BODY(sA);
        }
    }
#undef STEP_BODY

#define MERGE(mc, zc, ac)                                                      \
    {   float mo = __shfl_xor(mc, 32, 64);                                     \
        float zo = __shfl_xor(zc, 32, 64);                                     \
        float ao = __shfl_xor(ac, 32, 64);                                     \
        float M  = fmaxf(mc, mo);                                              \
        float S  = (mc >= M) ? 1.f : EXP2(mc - M);                             \
        float So = (mo >= M) ? 1.f : EXP2(mo - M);                             \
        zc = zc * S + zo * So;                                                 \
        ac = ac * S + ao * So;                                                 \
    }
    MERGE(m0, z0, a0);
    MERGE(m1, z1, a1);
    MERGE(m2, z2, a2);
    MERGE(m3, z3, a3);
#undef MERGE

    if (half == 0) {
        float o0 = (z0 > 0.f) ? a0 / z0 : 0.f;
        float o1 = (z1 > 0.f) ? a1 / z1 : 0.f;
        float o2 = (z2 > 0.f) ? a2 / z2 : 0.f;
        float o3 = (z3 > 0.f) ? a3 / z3 : 0.f;
        o0 = fmaxf(o0, neg_out * o0);
        o1 = fmaxf(o1, neg_out * o1);
        o2 = fmaxf(o2, neg_out * o2);
        o3 = fmaxf(o3, neg_out * o3);
        *(float4*)&xout[(size_t)node * 128 + cq * 4] = make_float4(o0, o1, o2, o3);
    }
}

// ---------------- final linear K=128 -> 64: LDS-staged Wct ----------------
// Wct (32KB) staged once + 32-node xs (16KB) = 48KB -> 3 blocks/CU.
// Each thread: 2 nodes x 4 channels.

__global__ __launch_bounds__(256) void k_lin64(const float* __restrict__ x,
                                               const float* __restrict__ Wct,
                                               const float* __restrict__ bc,
                                               float* __restrict__ y,
                                               __half* __restrict__ yh, int n) {
    __shared__ float ws[128 * 64];      // 32KB, row k: 64 outputs
    __shared__ float xs[32 * 128];      // 16KB
    int t = threadIdx.x;
    int node0 = blockIdx.x * 32;
    for (int i = t; i < 2048; i += 256)
        ((float4*)ws)[i] = ((const float4*)Wct)[i];
    for (int i = t; i < 1024; i += 256) {
        int row = i >> 5, c = i & 31;
        int gn = node0 + row;
        ((float4*)xs)[i] = (gn < n) ? ((const float4*)x)[(size_t)gn * 32 + c]
                                    : make_float4(0.f, 0.f, 0.f, 0.f);
    }
    __syncthreads();
    int l = t & 15;                     // output float4 index [0,16)
    int ng = (t >> 4) * 2;              // first of my 2 nodes
    float4 bb = ((const float4*)bc)[l];
    float4 a0 = bb, a1 = bb;
    const float4* xr0 = (const float4*)&xs[(ng + 0) * 128];
    const float4* xr1 = (const float4*)&xs[(ng + 1) * 128];
    #pragma unroll 4
    for (int k4 = 0; k4 < 32; ++k4) {
        float4 xv0 = xr0[k4];
        float4 xv1 = xr1[k4];
        const float* wr = &ws[k4 * 256];
        float4 w0 = ((const float4*)&wr[0])[l];
        float4 w1 = ((const float4*)&wr[64])[l];
        float4 w2 = ((const float4*)&wr[128])[l];
        float4 w3 = ((const float4*)&wr[192])[l];
        FMA4(a0, w0, xv0.x); FMA4(a0, w1, xv0.y); FMA4(a0, w2, xv0.z); FMA4(a0, w3, xv0.w);
        FMA4(a1, w0, xv1.x); FMA4(a1, w1, xv1.y); FMA4(a1, w2, xv1.z); FMA4(a1, w3, xv1.w);
    }
    union { __half2 h2[2]; uint2 u; } p;
    int gn = node0 + ng;
    if (gn + 0 < n) {
        ((float4*)&y[(size_t)(gn + 0) * 64])[l] = a0;
        p.h2[0] = __floats2half2_rn(a0.x, a0.y); p.h2[1] = __floats2half2_rn(a0.z, a0.w);
        *(uint2*)&yh[(size_t)(gn + 0) * 64 + l * 4] = p.u;
    }
    if (gn + 1 < n) {
        ((float4*)&y[(size_t)(gn + 1) * 64])[l] = a1;
        p.h2[0] = __floats2half2_rn(a1.x, a1.y); p.h2[1] = __floats2half2_rn(a1.z, a1.w);
        *(uint2*)&yh[(size_t)(gn + 1) * 64 + l * 4] = p.u;
    }
}

// ---------------- edge scores: sigmoid(dot(x[src], x[dst])), fp16 gather, 8 lanes/edge ----------------

__global__ __launch_bounds__(256) void k_edge_score(const __half* __restrict__ xh,
                                                    const int* __restrict__ src,
                                                    const int* __restrict__ dst,
                                                    float* __restrict__ out, int e_cnt) {
    int t = blockIdx.x * 256 + threadIdx.x;
    int e = t >> 3;
    int l = t & 7;
    if (e >= e_cnt) return;
    int u = src[e], v = dst[e];
    uint4 ua = ((const uint4*)&xh[(size_t)u * 64])[l];
    uint4 vb = ((const uint4*)&xh[(size_t)v * 64])[l];
    const __half2* pa = (const __half2*)&ua;
    const __half2* pb = (const __half2*)&vb;
    float d = 0.f;
    #pragma unroll
    for (int j = 0; j < 4; ++j) {
        float2 fa = __half22float2(pa[j]);
        float2 fb = __half22float2(pb[j]);
        d = fmaf(fa.x, fb.x, d);
        d = fmaf(fa.y, fb.y, d);
    }
    d += __shfl_xor(d, 1);
    d += __shfl_xor(d, 2);
    d += __shfl_xor(d, 4);
    if (l == 0) out[e] = 1.f / (1.f + __expf(-d));
}

// ---------------- launch ----------------

extern "C" void kernel_launch(void* const* d_in, const int* in_sizes, int n_in,
                              void* d_out, int out_size, void* d_ws, size_t ws_size,
                              hipStream_t stream) {
    const float* emb   = (const float*)d_in[0];
    const int*   ei    = (const int*)d_in[1];
    const float* W0    = (const float*)d_in[2];
    const float* b0    = (const float*)d_in[3];
    const float* attl0 = (const float*)d_in[4];
    const float* attr0 = (const float*)d_in[5];
    const float* W1    = (const float*)d_in[6];
    const float* b1    = (const float*)d_in[7];
    const float* attl1 = (const float*)d_in[8];
    const float* attr1 = (const float*)d_in[9];
    const float* pW1   = (const float*)d_in[10];
    const float* pb1   = (const float*)d_in[11];
    const float* pW2   = (const float*)d_in[12];
    const float* pb2   = (const float*)d_in[13];

    const int* src = ei;
    const int* dst = ei + N_EDGES;

    float* out = (float*)d_out;          // [E]
    float* xo  = out + N_EDGES;          // [N,64] fp32 node output

    char* ws = (char*)d_ws;
    size_t o = 0;
    auto alloc = [&](size_t bytes) {
        char* p = ws + o;
        o = (o + bytes + 255) & ~(size_t)255;
        return p;
    };
    int*    deg  = (int*)alloc((size_t)N_NODES * 4);
    int*    off  = (int*)alloc((size_t)(N_NODES + 1) * 4);
    int*    cur  = (int*)alloc((size_t)N_NODES * 4);
    int*    esrc = (int*)alloc((size_t)N_EDGES * 4);
    int*    bsum = (int*)alloc(64 * 4);
    int*    boff = (int*)alloc(64 * 4);
    __half* hbuf = (__half*)alloc((size_t)N_NODES * HC * 2);
    float*  xbuf = (float*)alloc((size_t)N_NODES * HC * 4);
    __half* yh   = (__half*)alloc((size_t)N_NODES * OUTD * 2);
    float*  Wt   = (float*)alloc((size_t)HC * HC * 4);
    float*  Wct  = (float*)alloc((size_t)HC * OUTD * 4);
    float*  bc   = (float*)alloc((size_t)OUTD * 4);
    (void)ws_size; (void)in_sizes; (void)n_in; (void)out_size;

    const int SCAN_NB = (N_NODES + 1023) / 1024;   // 49
    const int LIN_NB  = (N_NODES + 31) / 32;       // 1563

    // CSR by dst
    hipMemsetAsync(deg, 0, (size_t)N_NODES * 4, stream);
    k_deg <<<(N_EDGES + 255) / 256, 256, 0, stream>>>(dst, deg, N_EDGES);
    k_scan_up  <<<SCAN_NB, 1024, 0, stream>>>(deg, off, bsum, N_NODES);
    k_scan_mid <<<1, 64, 0, stream>>>(bsum, boff, SCAN_NB, off, N_NODES);
    k_scan_down<<<SCAN_NB, 1024, 0, stream>>>(off, boff, cur, N_NODES);
    k_fill<<<(N_EDGES + 255) / 256, 256, 0, stream>>>(src, dst, cur, esrc, N_EDGES);

    // GAT layer 0
    k_transpose<<<(HC * HC + 255) / 256, 256, 0, stream>>>(W0, Wt, HC, HC);
    k_lin128<<<LIN_NB, 256, 0, stream>>>(emb, Wt, b0, hbuf, N_NODES);
    k_gat_agg<<<(N_NODES + 3) / 4, 256, 0, stream>>>(hbuf, off, esrc, attl0, attr0,
                                                     xbuf, N_NODES, 0.01f);
    // GAT layer 1
    k_transpose<<<(HC * HC + 255) / 256, 256, 0, stream>>>(W1, Wt, HC, HC);
    k_lin128<<<LIN_NB, 256, 0, stream>>>(xbuf, Wt, b1, hbuf, N_NODES);
    k_gat_agg<<<(N_NODES + 3) / 4, 256, 0, stream>>>(hbuf, off, esrc, attl1, attr1,
                                                     xbuf, N_NODES, 0.01f);

    // post_mp (combined) + node output (fp32 + fp16 copy)
    k_combine<<<(HC * OUTD + 255) / 256, 256, 0, stream>>>(pW1, pb1, pW2, pb2, Wct, bc);
    k_lin64<<<LIN_NB, 256, 0, stream>>>(xbuf, Wct, bc, xo, yh, N_NODES);

    // edge scores
    k_edge_score<<<(N_EDGES * 8 + 255) / 256, 256, 0, stream>>>(yh, src, dst, out, N_EDGES);
}

// Round 5
// 298.977 us; speedup vs baseline: 1.3775x; 1.0755x over previous
//
#include <hip/hip_runtime.h>
#include <hip/hip_bf16.h>
#include <hip/hip_fp16.h>
#include <math.h>

#define N_NODES 50000
#define N_EDGES 800000
#define HC      128     // HEADS*HID
#define OUTD    64

// fast exp2: single v_exp_f32
#if defined(__has_builtin)
#if __has_builtin(__builtin_amdgcn_exp2f)
#define EXP2(x) __builtin_amdgcn_exp2f(x)
#endif
#endif
#ifndef EXP2
#define EXP2(x) __expf((x) * 0.69314718055994531f)
#endif

// ---------------- CSR build ----------------

__global__ void k_deg(const int* __restrict__ dst, int* __restrict__ deg, int e_cnt) {
    int e = blockIdx.x * blockDim.x + threadIdx.x;
    if (e < e_cnt) atomicAdd(&deg[dst[e]], 1);
}

// hierarchical scan: 49 blocks of 1024 -> 1 wave -> add-down
__global__ void k_scan_up(const int* __restrict__ deg, int* __restrict__ off,
                          int* __restrict__ bsum, int n) {
    __shared__ int wsum[16];
    __shared__ int wexc[16];
    const int lane = threadIdx.x & 63;
    const int wid  = threadIdx.x >> 6;
    int i = blockIdx.x * 1024 + threadIdx.x;
    int v = (i < n) ? deg[i] : 0;
    int incl = v;
    #pragma unroll
    for (int s = 1; s < 64; s <<= 1) {
        int t = __shfl_up(incl, s, 64);
        if (lane >= s) incl += t;
    }
    if (lane == 63) wsum[wid] = incl;
    __syncthreads();
    if (wid == 0 && lane < 16) {
        int w = wsum[lane];
        int wi = w;
        #pragma unroll
        for (int s = 1; s < 16; s <<= 1) {
            int t = __shfl_up(wi, s, 64);
            if (lane >= s) wi += t;
        }
        wexc[lane] = wi - w;
    }
    __syncthreads();
    int ex = wexc[wid] + incl - v;     // exclusive within block
    if (i < n) off[i] = ex;
    if (threadIdx.x == 1023) bsum[blockIdx.x] = ex + v;   // block total
}

__global__ void k_scan_mid(const int* __restrict__ bsum, int* __restrict__ boff,
                           int nb, int* __restrict__ off, int n) {
    int lane = threadIdx.x;   // 64 threads, nb <= 64
    int v = (lane < nb) ? bsum[lane] : 0;
    int incl = v;
    #pragma unroll
    for (int s = 1; s < 64; s <<= 1) {
        int t = __shfl_up(incl, s, 64);
        if (lane >= s) incl += t;
    }
    if (lane < nb) boff[lane] = incl - v;
    if (lane == 63) off[n] = incl;     // grand total
}

__global__ void k_scan_down(int* __restrict__ off, const int* __restrict__ boff,
                            int* __restrict__ cur, int n) {
    int i = blockIdx.x * 1024 + threadIdx.x;
    if (i < n) {
        int o = off[i] + boff[blockIdx.x];
        off[i] = o;
        cur[i] = o;
    }
}

__global__ void k_fill(const int* __restrict__ src, const int* __restrict__ dst,
                       int* __restrict__ cur, int* __restrict__ esrc, int e_cnt) {
    int e = blockIdx.x * blockDim.x + threadIdx.x;
    if (e < e_cnt) {
        int p = atomicAdd(&cur[dst[e]], 1);
        esrc[p] = src[e];
    }
}

// ---------------- weight prep (fused: 2 transposes + post_mp combine) ----------------

__global__ void k_prep(const float* __restrict__ W0, const float* __restrict__ W1,
                       const float* __restrict__ pW1, const float* __restrict__ pb1,
                       const float* __restrict__ pW2, const float* __restrict__ pb2,
                       float* __restrict__ Wt0, float* __restrict__ Wt1,
                       float* __restrict__ Wct, float* __restrict__ bc) {
    int i = blockIdx.x * blockDim.x + threadIdx.x;
    if (i < HC * HC) {
        int r = i >> 7, c = i & 127;
        Wt0[c * HC + r] = W0[i];
        Wt1[c * HC + r] = W1[i];
    } else if (i < HC * HC + HC * OUTD) {
        int j = i - HC * HC;
        int k = j >> 6, o = j & 63;
        float s = 0.f;
        for (int m = 0; m < 64; ++m) s += pW2[o * 64 + m] * pW1[m * 128 + k];
        Wct[k * 64 + o] = s;
    } else if (i < HC * HC + HC * OUTD + OUTD) {
        int o = i - HC * HC - HC * OUTD;
        float s = pb2[o];
        for (int m = 0; m < 64; ++m) s += pW2[o * 64 + m] * pb1[m];
        bc[o] = s;
    }
}

// ---------------- linear: h = x @ Wt + b, K=128, OC=128, out fp16 ----------------
// LDS-staged weights. 32 nodes/block, Wt staged in two 32KB K-chunks,
// x staged once (16KB). 48KB LDS -> 3 blocks/CU.
// NOTE: macro params must not be named x/y/z/w (preprocessor substitutes
// member-access tokens -- round 3's compile failure).

#define FMA4(acc, wv, sv)                                                      \
    acc.x = fmaf(wv.x, sv, acc.x); acc.y = fmaf(wv.y, sv, acc.y);              \
    acc.z = fmaf(wv.z, sv, acc.z); acc.w = fmaf(wv.w, sv, acc.w);

__global__ __launch_bounds__(256) void k_lin128(const float* __restrict__ x,
                                                const float* __restrict__ Wt,
                                                const float* __restrict__ bias,
                                                __half* __restrict__ h, int n) {
    __shared__ float ws[64 * 128];      // 32KB: one K-chunk of Wt (rows = k)
    __shared__ float xs[32 * 128];      // 16KB: 32 node rows
    int t = threadIdx.x;
    int node0 = blockIdx.x * 32;
    for (int i = t; i < 1024; i += 256) {
        int row = i >> 5, c = i & 31;
        int gn = node0 + row;
        ((float4*)xs)[i] = (gn < n) ? ((const float4*)x)[(size_t)gn * 32 + c]
                                    : make_float4(0.f, 0.f, 0.f, 0.f);
    }
    int c4 = t & 31;                    // output float4 index [0,32)
    int ng = (t >> 5) * 4;              // first of my 4 nodes
    float4 bb = ((const float4*)bias)[c4];
    float4 a0 = bb, a1 = bb, a2 = bb, a3 = bb;
    const float4* xr0 = (const float4*)&xs[(ng + 0) * 128];
    const float4* xr1 = (const float4*)&xs[(ng + 1) * 128];
    const float4* xr2 = (const float4*)&xs[(ng + 2) * 128];
    const float4* xr3 = (const float4*)&xs[(ng + 3) * 128];

    for (int chunk = 0; chunk < 2; ++chunk) {
        __syncthreads();                // x ready (it=0) / ws no longer read (it=1)
        const float4* wsrc = (const float4*)&Wt[chunk * 64 * 128];
        for (int i = t; i < 2048; i += 256)
            ((float4*)ws)[i] = wsrc[i];
        __syncthreads();
        int kb = chunk * 16;
        #pragma unroll 4
        for (int k4 = 0; k4 < 16; ++k4) {
            float4 xv0 = xr0[kb + k4];
            float4 xv1 = xr1[kb + k4];
            float4 xv2 = xr2[kb + k4];
            float4 xv3 = xr3[kb + k4];
            const float* wr = &ws[k4 * 512];
            float4 w0 = ((const float4*)&wr[0])[c4];
            float4 w1 = ((const float4*)&wr[128])[c4];
            float4 w2 = ((const float4*)&wr[256])[c4];
            float4 w3 = ((const float4*)&wr[384])[c4];
            FMA4(a0, w0, xv0.x); FMA4(a0, w1, xv0.y); FMA4(a0, w2, xv0.z); FMA4(a0, w3, xv0.w);
            FMA4(a1, w0, xv1.x); FMA4(a1, w1, xv1.y); FMA4(a1, w2, xv1.z); FMA4(a1, w3, xv1.w);
            FMA4(a2, w0, xv2.x); FMA4(a2, w1, xv2.y); FMA4(a2, w2, xv2.z); FMA4(a2, w3, xv2.w);
            FMA4(a3, w0, xv3.x); FMA4(a3, w1, xv3.y); FMA4(a3, w2, xv3.z); FMA4(a3, w3, xv3.w);
        }
    }

    union { __half2 h2[2]; uint2 u; } p;
    int gn = node0 + ng;
    if (gn + 0 < n) { p.h2[0] = __floats2half2_rn(a0.x, a0.y); p.h2[1] = __floats2half2_rn(a0.z, a0.w);
                      *(uint2*)&h[(size_t)(gn + 0) * 128 + c4 * 4] = p.u; }
    if (gn + 1 < n) { p.h2[0] = __floats2half2_rn(a1.x, a1.y); p.h2[1] = __floats2half2_rn(a1.z, a1.w);
                      *(uint2*)&h[(size_t)(gn + 1) * 128 + c4 * 4] = p.u; }
    if (gn + 2 < n) { p.h2[0] = __floats2half2_rn(a2.x, a2.y); p.h2[1] = __floats2half2_rn(a2.z, a2.w);
                      *(uint2*)&h[(size_t)(gn + 2) * 128 + c4 * 4] = p.u; }
    if (gn + 3 < n) { p.h2[0] = __floats2half2_rn(a3.x, a3.y); p.h2[1] = __floats2half2_rn(a3.z, a3.w);
                      *(uint2*)&h[(size_t)(gn + 3) * 128 + c4 * 4] = p.u; }
}

// ---------------- GAT aggregate ----------------
// One wave per dst node, two half-waves by edge parity (lane = 32*half + cq,
// cq owns 4 channels). Max-free softmax: softmax is scale-invariant, and the
// log2-domain scores here are O(+-5), so a/z with e = 2^t directly equals the
// max-shifted softmax (no overflow/flush). Leaky folded into a second FMA:
// leaky(s) = max(fma(al,f,ar), fma(.2al,f,.2ar)). Both FMAs + the accumulate
// take the fp16 operand directly (v_fma_mix). Per channel-edge: 3 fma + 1 max
// + 1 exp + 1 add. Parity merge = plain adds (shared implicit reference 0).
// Safety net: if any z is inf/NaN (overflow) or 0 with deg>0 (total
// underflow), the wave redoes the node with a two-pass max-shifted loop.

__global__ __launch_bounds__(256) void k_gat_agg(const __half* __restrict__ h,
                                                 const int* __restrict__ off,
                                                 const int* __restrict__ esrc,
                                                 const float* __restrict__ attl,
                                                 const float* __restrict__ attr,
                                                 float* __restrict__ xout, int n,
                                                 float neg_out) {
    const float L2E = 1.4426950408889634f;
    int wid  = threadIdx.x >> 6;
    int lane = threadIdx.x & 63;
    int node = blockIdx.x * 4 + wid;
    if (node >= n) return;
    int half = lane >> 5;               // edge parity this half-wave owns
    int cq   = lane & 31;               // channel quad index
    const char* hb = (const char*)h + ((uint32_t)cq << 3);   // per-lane base

    float4 alv = ((const float4*)attl)[cq];
    float4 arv = ((const float4*)attr)[cq];
    uint2 hdr = *(const uint2*)(hb + ((uint32_t)node << 8));
    float2 hd01 = __half22float2(((const __half2*)&hdr)[0]);
    float2 hd23 = __half22float2(((const __half2*)&hdr)[1]);
    float al0 = alv.x * L2E, al1 = alv.y * L2E;
    float al2 = alv.z * L2E, al3 = alv.w * L2E;
    float ar0 = arv.x * hd01.x * L2E, ar1 = arv.y * hd01.y * L2E;
    float ar2 = arv.z * hd23.x * L2E, ar3 = arv.w * hd23.y * L2E;
    float al0q = 0.2f * al0, al1q = 0.2f * al1, al2q = 0.2f * al2, al3q = 0.2f * al3;
    float ar0q = 0.2f * ar0, ar1q = 0.2f * ar1, ar2q = 0.2f * ar2, ar3q = 0.2f * ar3;

    float z0 = 0.f, z1 = 0.f, z2 = 0.f, z3 = 0.f;
    float a0 = 0.f, a1 = 0.f, a2 = 0.f, a3 = 0.f;

    int beg = off[node], end = off[node + 1];

#define STEP(sAv)                                                              \
    {   uint2 hv = *(const uint2*)(hb + ((uint32_t)(sAv) << 8));               \
        float2 f01 = __half22float2(((const __half2*)&hv)[0]);                 \
        float2 f23 = __half22float2(((const __half2*)&hv)[1]);                 \
        float t0 = fmaf(al0, f01.x, ar0), u0 = fmaf(al0q, f01.x, ar0q);        \
        float t1 = fmaf(al1, f01.y, ar1), u1 = fmaf(al1q, f01.y, ar1q);        \
        float t2 = fmaf(al2, f23.x, ar2), u2 = fmaf(al2q, f23.x, ar2q);        \
        float t3 = fmaf(al3, f23.y, ar3), u3 = fmaf(al3q, f23.y, ar3q);        \
        float e0 = EXP2(fmaxf(t0, u0)), e1 = EXP2(fmaxf(t1, u1));              \
        float e2 = EXP2(fmaxf(t2, u2)), e3 = EXP2(fmaxf(t3, u3));              \
        z0 += e0; z1 += e1; z2 += e2; z3 += e3;                                \
        a0 = fmaf(e0, f01.x, a0); a1 = fmaf(e1, f01.y, a1);                    \
        a2 = fmaf(e2, f23.x, a2); a3 = fmaf(e3, f23.y, a3);                    \
    }

    for (int cbeg = beg; cbeg < end; cbeg += 64) {
        int cnt = end - cbeg; if (cnt > 64) cnt = 64;
        int myS = (cbeg + lane < end) ? esrc[cbeg + lane] : 0;
        int fullp = cnt >> 1;           // steps where both halves have an edge
        #pragma unroll 4
        for (int t = 0; t < fullp; ++t) {
            int sA = __shfl(myS, 2 * t + half, 64);   // all 64 lanes active
            STEP(sA);
        }
        if (cnt & 1) {                  // one leftover even-parity edge
            int sA = __shfl(myS, cnt - 1, 64);        // shfl with full exec
            if (half == 0) STEP(sA);
        }
    }
#undef STEP

    // validity: overflow -> z inf/NaN; total underflow -> z==0 with edges
    float zs = z0 + z1 + z2 + z3;
    bool bad = !(zs < 3.0e38f);
    if (beg < end)
        bad = bad || !((z0 > 0.f) && (z1 > 0.f) && (z2 > 0.f) && (z3 > 0.f));

    if (__any(bad)) {
        // slow safe path (~never): two-pass max-shifted softmax; every lane
        // walks ALL edges, so both halves hold identical full sums (no merge).
        float m0 = -1e30f, m1 = -1e30f, m2 = -1e30f, m3 = -1e30f;
        for (int cbeg = beg; cbeg < end; cbeg += 64) {
            int cnt = end - cbeg; if (cnt > 64) cnt = 64;
            int myS = (cbeg + lane < end) ? esrc[cbeg + lane] : 0;
            for (int t = 0; t < cnt; ++t) {
                int sA = __shfl(myS, t, 64);
                uint2 hv = *(const uint2*)(hb + ((uint32_t)sA << 8));
                float2 f01 = __half22float2(((const __half2*)&hv)[0]);
                float2 f23 = __half22float2(((const __half2*)&hv)[1]);
                m0 = fmaxf(m0, fmaxf(fmaf(al0, f01.x, ar0), fmaf(al0q, f01.x, ar0q)));
                m1 = fmaxf(m1, fmaxf(fmaf(al1, f01.y, ar1), fmaf(al1q, f01.y, ar1q)));
                m2 = fmaxf(m2, fmaxf(fmaf(al2, f23.x, ar2), fmaf(al2q, f23.x, ar2q)));
                m3 = fmaxf(m3, fmaxf(fmaf(al3, f23.y, ar3), fmaf(al3q, f23.y, ar3q)));
            }
        }
        z0 = z1 = z2 = z3 = 0.f;
        a0 = a1 = a2 = a3 = 0.f;
        for (int cbeg = beg; cbeg < end; cbeg += 64) {
            int cnt = end - cbeg; if (cnt > 64) cnt = 64;
            int myS = (cbeg + lane < end) ? esrc[cbeg + lane] : 0;
            for (int t = 0; t < cnt; ++t) {
                int sA = __shfl(myS, t, 64);
                uint2 hv = *(const uint2*)(hb + ((uint32_t)sA << 8));
                float2 f01 = __half22float2(((const __half2*)&hv)[0]);
                float2 f23 = __half22float2(((const __half2*)&hv)[1]);
                float e0 = EXP2(fmaxf(fmaf(al0, f01.x, ar0), fmaf(al0q, f01.x, ar0q)) - m0);
                float e1 = EXP2(fmaxf(fmaf(al1, f01.y, ar1), fmaf(al1q, f01.y, ar1q)) - m1);
                float e2 = EXP2(fmaxf(fmaf(al2, f23.x, ar2), fmaf(al2q, f23.x, ar2q)) - m2);
                float e3 = EXP2(fmaxf(fmaf(al3, f23.y, ar3), fmaf(al3q, f23.y, ar3q)) - m3);
                z0 += e0; z1 += e1; z2 += e2; z3 += e3;
                a0 = fmaf(e0, f01.x, a0); a1 = fmaf(e1, f01.y, a1);
                a2 = fmaf(e2, f23.x, a2); a3 = fmaf(e3, f23.y, a3);
            }
        }
    } else {
        // merge parity halves: plain adds (shared implicit reference)
        z0 += __shfl_xor(z0, 32, 64); z1 += __shfl_xor(z1, 32, 64);
        z2 += __shfl_xor(z2, 32, 64); z3 += __shfl_xor(z3, 32, 64);
        a0 += __shfl_xor(a0, 32, 64); a1 += __shfl_xor(a1, 32, 64);
        a2 += __shfl_xor(a2, 32, 64); a3 += __shfl_xor(a3, 32, 64);
    }

    if (half == 0) {
        float o0 = (z0 > 0.f) ? a0 / z0 : 0.f;
        float o1 = (z1 > 0.f) ? a1 / z1 : 0.f;
        float o2 = (z2 > 0.f) ? a2 / z2 : 0.f;
        float o3 = (z3 > 0.f) ? a3 / z3 : 0.f;
        o0 = fmaxf(o0, neg_out * o0);
        o1 = fmaxf(o1, neg_out * o1);
        o2 = fmaxf(o2, neg_out * o2);
        o3 = fmaxf(o3, neg_out * o3);
        *(float4*)&xout[(size_t)node * 128 + cq * 4] = make_float4(o0, o1, o2, o3);
    }
}

// ---------------- final linear K=128 -> 64: LDS-staged Wct ----------------

__global__ __launch_bounds__(256) void k_lin64(const float* __restrict__ x,
                                               const float* __restrict__ Wct,
                                               const float* __restrict__ bc,
                                               float* __restrict__ y,
                                               __half* __restrict__ yh, int n) {
    __shared__ float ws[128 * 64];      // 32KB, row k: 64 outputs
    __shared__ float xs[32 * 128];      // 16KB
    int t = threadIdx.x;
    int node0 = blockIdx.x * 32;
    for (int i = t; i < 2048; i += 256)
        ((float4*)ws)[i] = ((const float4*)Wct)[i];
    for (int i = t; i < 1024; i += 256) {
        int row = i >> 5, c = i & 31;
        int gn = node0 + row;
        ((float4*)xs)[i] = (gn < n) ? ((const float4*)x)[(size_t)gn * 32 + c]
                                    : make_float4(0.f, 0.f, 0.f, 0.f);
    }
    __syncthreads();
    int l = t & 15;                     // output float4 index [0,16)
    int ng = (t >> 4) * 2;              // first of my 2 nodes
    float4 bb = ((const float4*)bc)[l];
    float4 a0 = bb, a1 = bb;
    const float4* xr0 = (const float4*)&xs[(ng + 0) * 128];
    const float4* xr1 = (const float4*)&xs[(ng + 1) * 128];
    #pragma unroll 4
    for (int k4 = 0; k4 < 32; ++k4) {
        float4 xv0 = xr0[k4];
        float4 xv1 = xr1[k4];
        const float* wr = &ws[k4 * 256];
        float4 w0 = ((const float4*)&wr[0])[l];
        float4 w1 = ((const float4*)&wr[64])[l];
        float4 w2 = ((const float4*)&wr[128])[l];
        float4 w3 = ((const float4*)&wr[192])[l];
        FMA4(a0, w0, xv0.x); FMA4(a0, w1, xv0.y); FMA4(a0, w2, xv0.z); FMA4(a0, w3, xv0.w);
        FMA4(a1, w0, xv1.x); FMA4(a1, w1, xv1.y); FMA4(a1, w2, xv1.z); FMA4(a1, w3, xv1.w);
    }
    union { __half2 h2[2]; uint2 u; } p;
    int gn = node0 + ng;
    if (gn + 0 < n) {
        ((float4*)&y[(size_t)(gn + 0) * 64])[l] = a0;
        p.h2[0] = __floats2half2_rn(a0.x, a0.y); p.h2[1] = __floats2half2_rn(a0.z, a0.w);
        *(uint2*)&yh[(size_t)(gn + 0) * 64 + l * 4] = p.u;
    }
    if (gn + 1 < n) {
        ((float4*)&y[(size_t)(gn + 1) * 64])[l] = a1;
        p.h2[0] = __floats2half2_rn(a1.x, a1.y); p.h2[1] = __floats2half2_rn(a1.z, a1.w);
        *(uint2*)&yh[(size_t)(gn + 1) * 64 + l * 4] = p.u;
    }
}

// ---------------- edge scores: sigmoid(dot(x[src], x[dst])), fp16 gather, 8 lanes/edge ----------------

__global__ __launch_bounds__(256) void k_edge_score(const __half* __restrict__ xh,
                                                    const int* __restrict__ src,
                                                    const int* __restrict__ dst,
                                                    float* __restrict__ out, int e_cnt) {
    int t = blockIdx.x * 256 + threadIdx.x;
    int e = t >> 3;
    int l = t & 7;
    if (e >= e_cnt) return;
    int u = src[e], v = dst[e];
    uint4 ua = ((const uint4*)&xh[(size_t)u * 64])[l];
    uint4 vb = ((const uint4*)&xh[(size_t)v * 64])[l];
    const __half2* pa = (const __half2*)&ua;
    const __half2* pb = (const __half2*)&vb;
    float d = 0.f;
    #pragma unroll
    for (int j = 0; j < 4; ++j) {
        float2 fa = __half22float2(pa[j]);
        float2 fb = __half22float2(pb[j]);
        d = fmaf(fa.x, fb.x, d);
        d = fmaf(fa.y, fb.y, d);
    }
    d += __shfl_xor(d, 1);
    d += __shfl_xor(d, 2);
    d += __shfl_xor(d, 4);
    if (l == 0) out[e] = 1.f / (1.f + __expf(-d));
}

// ---------------- launch ----------------

extern "C" void kernel_launch(void* const* d_in, const int* in_sizes, int n_in,
                              void* d_out, int out_size, void* d_ws, size_t ws_size,
                              hipStream_t stream) {
    const float* emb   = (const float*)d_in[0];
    const int*   ei    = (const int*)d_in[1];
    const float* W0    = (const float*)d_in[2];
    const float* b0    = (const float*)d_in[3];
    const float* attl0 = (const float*)d_in[4];
    const float* attr0 = (const float*)d_in[5];
    const float* W1    = (const float*)d_in[6];
    const float* b1    = (const float*)d_in[7];
    const float* attl1 = (const float*)d_in[8];
    const float* attr1 = (const float*)d_in[9];
    const float* pW1   = (const float*)d_in[10];
    const float* pb1   = (const float*)d_in[11];
    const float* pW2   = (const float*)d_in[12];
    const float* pb2   = (const float*)d_in[13];

    const int* src = ei;
    const int* dst = ei + N_EDGES;

    float* out = (float*)d_out;          // [E]
    float* xo  = out + N_EDGES;          // [N,64] fp32 node output

    char* ws = (char*)d_ws;
    size_t o = 0;
    auto alloc = [&](size_t bytes) {
        char* p = ws + o;
        o = (o + bytes + 255) & ~(size_t)255;
        return p;
    };
    int*    deg  = (int*)alloc((size_t)N_NODES * 4);
    int*    off  = (int*)alloc((size_t)(N_NODES + 1) * 4);
    int*    cur  = (int*)alloc((size_t)N_NODES * 4);
    int*    esrc = (int*)alloc((size_t)N_EDGES * 4);
    int*    bsum = (int*)alloc(64 * 4);
    int*    boff = (int*)alloc(64 * 4);
    __half* hbuf = (__half*)alloc((size_t)N_NODES * HC * 2);
    float*  xbuf = (float*)alloc((size_t)N_NODES * HC * 4);
    __half* yh   = (__half*)alloc((size_t)N_NODES * OUTD * 2);
    float*  Wt0  = (float*)alloc((size_t)HC * HC * 4);
    float*  Wt1  = (float*)alloc((size_t)HC * HC * 4);
    float*  Wct  = (float*)alloc((size_t)HC * OUTD * 4);
    float*  bc   = (float*)alloc((size_t)OUTD * 4);
    (void)ws_size; (void)in_sizes; (void)n_in; (void)out_size;

    const int SCAN_NB = (N_NODES + 1023) / 1024;   // 49
    const int LIN_NB  = (N_NODES + 31) / 32;       // 1563
    const int PREP_N  = HC * HC + HC * OUTD + OUTD;

    // weight prep (independent of everything else)
    k_prep<<<(PREP_N + 255) / 256, 256, 0, stream>>>(W0, W1, pW1, pb1, pW2, pb2,
                                                     Wt0, Wt1, Wct, bc);

    // CSR by dst
    hipMemsetAsync(deg, 0, (size_t)N_NODES * 4, stream);
    k_deg <<<(N_EDGES + 255) / 256, 256, 0, stream>>>(dst, deg, N_EDGES);
    k_scan_up  <<<SCAN_NB, 1024, 0, stream>>>(deg, off, bsum, N_NODES);
    k_scan_mid <<<1, 64, 0, stream>>>(bsum, boff, SCAN_NB, off, N_NODES);
    k_scan_down<<<SCAN_NB, 1024, 0, stream>>>(off, boff, cur, N_NODES);
    k_fill<<<(N_EDGES + 255) / 256, 256, 0, stream>>>(src, dst, cur, esrc, N_EDGES);

    // GAT layer 0
    k_lin128<<<LIN_NB, 256, 0, stream>>>(emb, Wt0, b0, hbuf, N_NODES);
    k_gat_agg<<<(N_NODES + 3) / 4, 256, 0, stream>>>(hbuf, off, esrc, attl0, attr0,
                                                     xbuf, N_NODES, 0.01f);
    // GAT layer 1
    k_lin128<<<LIN_NB, 256, 0, stream>>>(xbuf, Wt1, b1, hbuf, N_NODES);
    k_gat_agg<<<(N_NODES + 3) / 4, 256, 0, stream>>>(hbuf, off, esrc, attl1, attr1,
                                                     xbuf, N_NODES, 0.01f);

    // post_mp (combined) + node output (fp32 + fp16 copy)
    k_lin64<<<LIN_NB, 256, 0, stream>>>(xbuf, Wct, bc, xo, yh, N_NODES);

    // edge scores
    k_edge_score<<<(N_EDGES * 8 + 255) / 256, 256, 0, stream>>>(yh, src, dst, out, N_EDGES);
}